// Round 8
// baseline (237.924 us; speedup 1.0000x reference)
//
#include <hip/hip_runtime.h>
#include <hip/hip_bf16.h>

// DotProductNonLocalBlock: B=8, C=512, N=3136 (pad 3200), E=256.
// No softmax => fully associative. Factored with DATA-INDEPENDENT
// P = wo·wv, Qt = wq^T·wk, u = wo·bv, r = bk^T·wq, w = Wk^T·bq, κ = bk·bq:
//   G  = X·X^T   [bf16 MFMA, split-K=2 col-interleaved partials, symmetric mirror]
//   T  = Pd·Gp2 (K=1024 folds the reduce)
//   A2 = [T·Q + u·(Qt s)^T + (P s)·r^T]/N + u·r^T
//   a2 = [T·w + u·(s·w) + (P s)·κ]/N + u·κ + bo
//   Out = A2·X + a2 + X
// Round-8: all MFMA K-loops use an explicit double-buffered pipeline with raw
// s_barrier + manual s_waitcnt vmcnt(N) so next-tile global_load_lds stay in
// flight across the barrier (the __syncthreads vmcnt(0) drain was the stall).

typedef __attribute__((ext_vector_type(8))) __bf16 bf16x8;
typedef __attribute__((ext_vector_type(4))) float floatx4;

struct __align__(8) bh4 { __hip_bfloat16 x, y, z, w; };
struct __align__(16) bh8 { __hip_bfloat16 h[8]; };

__device__ __forceinline__ void load_lds16(const void* g, void* l) {
    __builtin_amdgcn_global_load_lds((const __attribute__((address_space(1))) void*)g,
                                     (__attribute__((address_space(3))) void*)l, 16, 0, 0);
}

// s_waitcnt vmcnt(N) only (lgkmcnt=15, expcnt=7 untouched). gfx9 encoding:
// vmcnt[3:0]=bits[3:0], expcnt=bits[6:4], lgkmcnt=bits[11:8], vmcnt[5:4]=bits[15:14].
#define WAIT_VM(N) __builtin_amdgcn_s_waitcnt(0x0F70 | (N))
#define BAR() __builtin_amdgcn_s_barrier()

// ---- fused data-independent precompute ----
__global__ __launch_bounds__(256)
void prep_all(const float* __restrict__ wo, const float* __restrict__ wv,
              const float* __restrict__ wq, const float* __restrict__ wk,
              const float* __restrict__ bq, const float* __restrict__ bk,
              const float* __restrict__ bv,
              __hip_bfloat16* __restrict__ Pdb, __hip_bfloat16* __restrict__ Qtb,
              float* __restrict__ u, float* __restrict__ r, float* __restrict__ w,
              float* __restrict__ kap, float* __restrict__ sv)
{
    const int tid = threadIdx.x;
    if (blockIdx.z == 2) {
        int blk = blockIdx.y * 8 + blockIdx.x;
        if (blk < 2) {
            int c = blk * 256 + tid;
            float su = 0.f, sr = 0.f, sw = 0.f;
            for (int e = 0; e < 256; ++e) {
                su = fmaf(wo[(long long)c * 256 + e], bv[e], su);
                sr = fmaf(bk[e], wq[(long long)e * 512 + c], sr);
                sw = fmaf(wk[(long long)e * 512 + c], bq[e], sw);
            }
            u[c] = su; r[c] = sr; w[c] = sw;
            if (c == 0) {
                float k2 = 0.f;
                for (int e = 0; e < 256; ++e) k2 = fmaf(bk[e], bq[e], k2);
                *kap = k2;
            }
        } else if (blk == 2) {
            float4* p = (float4*)sv;
            for (int i = tid; i < 1024; i += 256) p[i] = make_float4(0.f, 0.f, 0.f, 0.f);
        }
        return;
    }
    __shared__ __align__(16) float As[16][68];
    __shared__ __align__(16) float Bs[16][68];
    const int tx = tid & 15, ty = tid >> 4;
    const int m0 = blockIdx.y * 64, n0 = blockIdx.x * 64;
    const bool doQ = (blockIdx.z == 1);
    const int lk = tid >> 4, lc = (tid & 15) * 4;
    const int lr = tid >> 2, lk4 = (tid & 3) * 4;
    float acc[4][4] = {};
    for (int k0 = 0; k0 < 256; k0 += 16) {
        float4 av, bv4;
        if (doQ) {
            av = *(const float4*)&wq[(long long)(k0 + lk) * 512 + m0 + lc];
            bv4 = *(const float4*)&wk[(long long)(k0 + lk) * 512 + n0 + lc];
        } else {
            av = *(const float4*)&wo[(long long)(m0 + lr) * 256 + k0 + lk4];
            bv4 = *(const float4*)&wv[(long long)(k0 + lk) * 512 + n0 + lc];
        }
        __syncthreads();
        if (doQ) {
            *(float4*)&As[lk][lc] = av;
        } else {
            As[lk4 + 0][lr] = av.x; As[lk4 + 1][lr] = av.y;
            As[lk4 + 2][lr] = av.z; As[lk4 + 3][lr] = av.w;
        }
        *(float4*)&Bs[lk][lc] = bv4;
        __syncthreads();
#pragma unroll
        for (int kk = 0; kk < 16; ++kk) {
            float a[4], b[4];
#pragma unroll
            for (int i = 0; i < 4; ++i) { a[i] = As[kk][ty * 4 + i]; b[i] = Bs[kk][tx * 4 + i]; }
#pragma unroll
            for (int i = 0; i < 4; ++i)
#pragma unroll
                for (int j = 0; j < 4; ++j) acc[i][j] = fmaf(a[i], b[j], acc[i][j]);
        }
    }
    const int mo = m0 + ty * 4, no = n0 + tx * 4;
    if (doQ) {
#pragma unroll
        for (int i = 0; i < 4; ++i)
#pragma unroll
            for (int j = 0; j < 4; ++j)
                Qtb[(long long)(mo + i) * 512 + no + j] = __float2bfloat16(acc[i][j]);
    } else {
#pragma unroll
        for (int i = 0; i < 4; ++i)
#pragma unroll
            for (int j = 0; j < 4; ++j) {
                __hip_bfloat16 v = __float2bfloat16(acc[i][j]);
                Pdb[(long long)(mo + i) * 1024 + no + j] = v;
                Pdb[(long long)(mo + i) * 1024 + no + j + 512] = v;
            }
    }
}

// x [b][512][3136] fp32 -> xT [b][3200][512] bf16 + xnp [b][512][3200] bf16
//                        + s[b][c] += rowsums (atomic). 16B stores.
__global__ __launch_bounds__(256)
void transpose_conv(const float* __restrict__ x, __hip_bfloat16* __restrict__ xT,
                    __hip_bfloat16* __restrict__ xnp, float* __restrict__ s)
{
    __shared__ float t[64][65];
    const int b = blockIdx.z;
    const int n0 = blockIdx.x * 64, c0 = blockIdx.y * 64;
    const int tid = threadIdx.x;
    const int nch = tid & 7;
    const int cr  = tid >> 3;
    __hip_bfloat16* xTo = xT + (long long)b * 3200 * 512;
    __hip_bfloat16* xno = xnp + (long long)b * 512 * 3200;

    if (n0 >= 3136) {
        bh8 z8;
#pragma unroll
        for (int k = 0; k < 8; ++k) z8.h[k] = __float2bfloat16(0.f);
#pragma unroll
        for (int pass = 0; pass < 2; ++pass) {
            int rr = cr + 32 * pass;
            *(bh8*)&xno[(long long)(c0 + rr) * 3200 + n0 + nch * 8] = z8;
            *(bh8*)&xTo[(long long)(n0 + rr) * 512 + c0 + nch * 8] = z8;
        }
        return;
    }
    const float* xb = x + (long long)b * 512 * 3136;
#pragma unroll
    for (int pass = 0; pass < 2; ++pass) {
        const int cl = cr + 32 * pass;
        const int c = c0 + cl;
        const float* xr = xb + (long long)c * 3136 + n0 + nch * 8;
        float4 v0 = *(const float4*)xr;
        float4 v1 = *(const float4*)(xr + 4);
        bh8 o;
        o.h[0] = __float2bfloat16(v0.x); o.h[1] = __float2bfloat16(v0.y);
        o.h[2] = __float2bfloat16(v0.z); o.h[3] = __float2bfloat16(v0.w);
        o.h[4] = __float2bfloat16(v1.x); o.h[5] = __float2bfloat16(v1.y);
        o.h[6] = __float2bfloat16(v1.z); o.h[7] = __float2bfloat16(v1.w);
        *(bh8*)&xno[(long long)c * 3200 + n0 + nch * 8] = o;
        const int nl = nch * 8;
        t[nl + 0][cl] = v0.x; t[nl + 1][cl] = v0.y;
        t[nl + 2][cl] = v0.z; t[nl + 3][cl] = v0.w;
        t[nl + 4][cl] = v1.x; t[nl + 5][cl] = v1.y;
        t[nl + 6][cl] = v1.z; t[nl + 7][cl] = v1.w;
        float rs = v0.x + v0.y + v0.z + v0.w + v1.x + v1.y + v1.z + v1.w;
        rs += __shfl_xor(rs, 1, 8);
        rs += __shfl_xor(rs, 2, 8);
        rs += __shfl_xor(rs, 4, 8);
        if (nch == 0) atomicAdd(&s[b * 512 + c], rs);
    }
    __syncthreads();
#pragma unroll
    for (int pass = 0; pass < 2; ++pass) {
        const int nl = cr + 32 * pass;
        const int cc = nch * 8;
        bh8 o;
#pragma unroll
        for (int k = 0; k < 8; ++k) o.h[k] = __float2bfloat16(t[nl][cc + k]);
        *(bh8*)&xTo[(long long)(n0 + nl) * 512 + c0 + cc] = o;
    }
}

// Wave-per-output: ps = P·s, sq = Qt·s, a2 = [T·w + u(s·w) + ps·κ]/N + uκ + bo.
__global__ __launch_bounds__(256)
void vec2_kernel(const __hip_bfloat16* __restrict__ T, const __hip_bfloat16* __restrict__ Pdb,
                 const __hip_bfloat16* __restrict__ Qtb, const float* __restrict__ s,
                 const float* __restrict__ u, const float* __restrict__ w,
                 const float* __restrict__ kap, const float* __restrict__ bo,
                 float* __restrict__ ps, float* __restrict__ sq, float* __restrict__ a2)
{
    const int idx = blockIdx.x * 4 + (threadIdx.x >> 6);
    const int lane = threadIdx.x & 63;
    const int b = idx >> 9, c = idx & 511;
    const int j0 = lane * 8;
    const float* sb = s + b * 512;
    float4 s0 = *(const float4*)&sb[j0], s1 = *(const float4*)&sb[j0 + 4];
    float4 w0 = *(const float4*)&w[j0],  w1 = *(const float4*)&w[j0 + 4];
    bf16x8 pv = *(const bf16x8*)&Pdb[(long long)c * 1024 + j0];
    bf16x8 qv = *(const bf16x8*)&Qtb[(long long)c * 512 + j0];
    bf16x8 tv = *(const bf16x8*)&T[(long long)b * 262144 + (long long)c * 512 + j0];
    float sj[8] = {s0.x, s0.y, s0.z, s0.w, s1.x, s1.y, s1.z, s1.w};
    float wj[8] = {w0.x, w0.y, w0.z, w0.w, w1.x, w1.y, w1.z, w1.w};
    float aps = 0.f, asq = 0.f, atw = 0.f, asw = 0.f;
#pragma unroll
    for (int t = 0; t < 8; ++t) {
        aps = fmaf((float)pv[t], sj[t], aps);
        asq = fmaf((float)qv[t], sj[t], asq);
        atw = fmaf((float)tv[t], wj[t], atw);
        asw = fmaf(sj[t], wj[t], asw);
    }
#pragma unroll
    for (int m = 1; m < 64; m <<= 1) {
        aps += __shfl_xor(aps, m);
        asq += __shfl_xor(asq, m);
        atw += __shfl_xor(atw, m);
        asw += __shfl_xor(asw, m);
    }
    if (lane == 0) {
        ps[idx] = aps; sq[idx] = asq;
        float kp = *kap;
        a2[idx] = (atw + u[c] * asw + aps * kp) * (1.f / 3136.f) + u[c] * kp + bo[c];
    }
}

#define SWZ64(row) ((row) & 7)

// G GEMM, symmetric mirroring, pipelined dbuf. 64x64 tile, BK=64.
// Grid: x = batch + 8*ks, y = triangular pair index (36).
__global__ __launch_bounds__(256)
void mfma_g(const __hip_bfloat16* __restrict__ A, long long sA, int lda,
            __hip_bfloat16* __restrict__ C, long long sC, int ldc,
            int kLen)
{
    constexpr int BKT = 64;
    constexpr int CPR = BKT / 8;
    constexpr int NC = 64 * CPR / 256;   // 2
    __shared__ __hip_bfloat16 As[2][64 * BKT];
    __shared__ __hip_bfloat16 Bs[2][64 * BKT];
    const int tid = threadIdx.x;
    const int lane = tid & 63;
    const int w = tid >> 6;
    const int wm = (w >> 1) << 5;
    const int wn = (w & 1) << 5;
    const int ln = lane & 15;
    const int hi = lane >> 4;
    const int bx = blockIdx.x;
    const int batch = bx & 7, ks = bx >> 3;
    int p = blockIdx.y, mt = 0;
    while (p >= 8 - mt) { p -= 8 - mt; ++mt; }
    const int nt = mt + p;
    const int m0 = mt << 6, n0 = nt << 6;
    const long long k0 = (long long)ks * kLen;

    const __hip_bfloat16* gA[NC];
    const __hip_bfloat16* gB[NC];
#pragma unroll
    for (int q0 = 0; q0 < NC; ++q0) {
        int q = tid + 256 * q0;
        int row = q / CPR;
        int c = (q % CPR) ^ SWZ64(row);
        gA[q0] = A + batch * sA + (long long)(m0 + row) * lda + k0 + c * 8;
        gB[q0] = A + batch * sA + (long long)(n0 + row) * lda + k0 + c * 8;
    }
    floatx4 acc[2][2] = {};
    const int nK = kLen / BKT;

    // prologue: tile 0 into buffer 0 (4 loads/thread)
#pragma unroll
    for (int q0 = 0; q0 < NC; ++q0) {
        load_lds16(gA[q0], &As[0][(tid + 256 * q0) * 8]);
        load_lds16(gB[q0], &Bs[0][(tid + 256 * q0) * 8]);
        gA[q0] += BKT; gB[q0] += BKT;
    }
    for (int kt = 0; kt < nK; ++kt) {
        const int pb = kt & 1;
        if (kt + 1 < nK) {
#pragma unroll
            for (int q0 = 0; q0 < NC; ++q0) {
                load_lds16(gA[q0], &As[pb ^ 1][(tid + 256 * q0) * 8]);
                load_lds16(gB[q0], &Bs[pb ^ 1][(tid + 256 * q0) * 8]);
                gA[q0] += BKT; gB[q0] += BKT;
            }
            WAIT_VM(4);   // tile-kt loads done; next-tile (4) still in flight
        } else {
            WAIT_VM(0);
        }
        BAR();
        const __hip_bfloat16* Ab = &As[pb][0];
        const __hip_bfloat16* Bb = &Bs[pb][0];
#pragma unroll
        for (int kk = 0; kk < BKT / 32; ++kk) {
            const int cidx = kk * 4 + hi;
            bf16x8 af[2], bfr[2];
#pragma unroll
            for (int i = 0; i < 2; ++i) {
                int row = wm + i * 16 + ln;
                af[i] = *(const bf16x8*)(Ab + row * BKT + ((cidx ^ SWZ64(row)) << 3));
            }
#pragma unroll
            for (int j = 0; j < 2; ++j) {
                int row = wn + j * 16 + ln;
                bfr[j] = *(const bf16x8*)(Bb + row * BKT + ((cidx ^ SWZ64(row)) << 3));
            }
#pragma unroll
            for (int i = 0; i < 2; ++i)
#pragma unroll
                for (int j = 0; j < 2; ++j)
                    acc[i][j] = __builtin_amdgcn_mfma_f32_16x16x32_bf16(af[i], bfr[j], acc[i][j], 0, 0, 0);
        }
        BAR();   // all waves done reading buf pb before it is overwritten at kt+2
    }

    __hip_bfloat16* Cb = C + batch * sC + ks * 512;
#pragma unroll
    for (int i = 0; i < 2; ++i) {
        int mb = m0 + wm + i * 16 + hi * 4;
#pragma unroll
        for (int j = 0; j < 2; ++j) {
            int nl = n0 + wn + j * 16 + ln;
            bh4 mv;
            mv.x = __float2bfloat16(acc[i][j][0]);
            mv.y = __float2bfloat16(acc[i][j][1]);
            mv.z = __float2bfloat16(acc[i][j][2]);
            mv.w = __float2bfloat16(acc[i][j][3]);
            Cb[(long long)(mb + 0) * ldc + nl] = mv.x;
            Cb[(long long)(mb + 1) * ldc + nl] = mv.y;
            Cb[(long long)(mb + 2) * ldc + nl] = mv.z;
            Cb[(long long)(mb + 3) * ldc + nl] = mv.w;
            if (mt != nt)
                *(bh4*)&Cb[(long long)nl * ldc + mb] = mv;
        }
    }
}

// Small MFMA GEMM, pipelined dbuf. 64x64 tile, BK=64.
// MODE 5: plain bf16 store. MODE 6: A2 epilogue.
template<int MODE>
__global__ __launch_bounds__(256)
void mfma_sm(const __hip_bfloat16* __restrict__ A, long long sA, int lda,
             const __hip_bfloat16* __restrict__ B, long long sB, int ldb,
             __hip_bfloat16* __restrict__ C, long long sC, int ldc,
             const float* __restrict__ pu, const float* __restrict__ pr,
             const float* __restrict__ pps, const float* __restrict__ psq,
             int kLen)
{
    constexpr int BKT = 64;
    constexpr int CPR = BKT / 8;
    constexpr int NC = 64 * CPR / 256;   // 2
    __shared__ __hip_bfloat16 As[2][64 * BKT];
    __shared__ __hip_bfloat16 Bs[2][64 * BKT];
    const int tid = threadIdx.x;
    const int lane = tid & 63;
    const int w = tid >> 6;
    const int wm = (w >> 1) << 5;
    const int wn = (w & 1) << 5;
    const int ln = lane & 15;
    const int hi = lane >> 4;
    const int batch = blockIdx.x;
    const int m0 = blockIdx.z << 6;
    const int n0 = blockIdx.y << 6;

    const __hip_bfloat16* gA[NC];
    const __hip_bfloat16* gB[NC];
#pragma unroll
    for (int q0 = 0; q0 < NC; ++q0) {
        int q = tid + 256 * q0;
        int row = q / CPR;
        int c = (q % CPR) ^ SWZ64(row);
        gA[q0] = A + batch * sA + (long long)(m0 + row) * lda + c * 8;
        gB[q0] = B + batch * sB + (long long)(n0 + row) * ldb + c * 8;
    }
    floatx4 acc[2][2] = {};
    const int nK = kLen / BKT;

#pragma unroll
    for (int q0 = 0; q0 < NC; ++q0) {
        load_lds16(gA[q0], &As[0][(tid + 256 * q0) * 8]);
        load_lds16(gB[q0], &Bs[0][(tid + 256 * q0) * 8]);
        gA[q0] += BKT; gB[q0] += BKT;
    }
    for (int kt = 0; kt < nK; ++kt) {
        const int pb = kt & 1;
        if (kt + 1 < nK) {
#pragma unroll
            for (int q0 = 0; q0 < NC; ++q0) {
                load_lds16(gA[q0], &As[pb ^ 1][(tid + 256 * q0) * 8]);
                load_lds16(gB[q0], &Bs[pb ^ 1][(tid + 256 * q0) * 8]);
                gA[q0] += BKT; gB[q0] += BKT;
            }
            WAIT_VM(4);
        } else {
            WAIT_VM(0);
        }
        BAR();
        const __hip_bfloat16* Ab = &As[pb][0];
        const __hip_bfloat16* Bb = &Bs[pb][0];
#pragma unroll
        for (int kk = 0; kk < BKT / 32; ++kk) {
            const int cidx = kk * 4 + hi;
            bf16x8 af[2], bfr[2];
#pragma unroll
            for (int i = 0; i < 2; ++i) {
                int row = wm + i * 16 + ln;
                af[i] = *(const bf16x8*)(Ab + row * BKT + ((cidx ^ SWZ64(row)) << 3));
            }
#pragma unroll
            for (int j = 0; j < 2; ++j) {
                int row = wn + j * 16 + ln;
                bfr[j] = *(const bf16x8*)(Bb + row * BKT + ((cidx ^ SWZ64(row)) << 3));
            }
#pragma unroll
            for (int i = 0; i < 2; ++i)
#pragma unroll
                for (int j = 0; j < 2; ++j)
                    acc[i][j] = __builtin_amdgcn_mfma_f32_16x16x32_bf16(af[i], bfr[j], acc[i][j], 0, 0, 0);
        }
        BAR();
    }

    __hip_bfloat16* Cb = C + batch * sC;
#pragma unroll
    for (int i = 0; i < 2; ++i) {
        int mb = m0 + wm + i * 16 + hi * 4;
#pragma unroll
        for (int r = 0; r < 4; ++r) {
#pragma unroll
            for (int j = 0; j < 2; ++j) {
                int nl = n0 + wn + j * 16 + ln;
                float v = acc[i][j][r];
                if (MODE == 6) {
                    float uu = pu[mb + r], rr = pr[nl];
                    v = (v + uu * psq[batch * 512 + nl] + pps[batch * 512 + mb + r] * rr)
                        * (1.f / 3136.f) + uu * rr;
                }
                Cb[(long long)(mb + r) * ldc + nl] = __float2bfloat16(v);
            }
        }
    }
}

// Final MFMA GEMM, pipelined dbuf: 64(M)x128(N), 4 waves (64x32), BK=64.
// Grid: x = batch (XCD affinity), y = n-tile (25), z = m-tile (8).
__global__ __launch_bounds__(256)
void mfma64(const __hip_bfloat16* __restrict__ A, long long sA, int lda,
            const __hip_bfloat16* __restrict__ B, long long sB, int ldb,
            float* __restrict__ C, long long sC, int ldc,
            const float* __restrict__ bias, int sBias,
            const float* __restrict__ xres, long long sX,
            int kLen, int Nreal)
{
    constexpr int BKT = 64;
    constexpr int CPR = BKT / 8;
    constexpr int NA = 64 * CPR / 256;    // 2
    constexpr int NB = 128 * CPR / 256;   // 4
    __shared__ __hip_bfloat16 As[2][64 * BKT];
    __shared__ __hip_bfloat16 Bs[2][128 * BKT];
    const int tid = threadIdx.x;
    const int lane = tid & 63;
    const int w = tid >> 6;
    const int ln = lane & 15;
    const int hi = lane >> 4;
    const int batch = blockIdx.x;
    const int m0 = blockIdx.z << 6;
    const int n0 = blockIdx.y << 7;

    const __hip_bfloat16* gA[NA];
    const __hip_bfloat16* gB[NB];
#pragma unroll
    for (int q0 = 0; q0 < NA; ++q0) {
        int q = tid + 256 * q0;
        int row = q / CPR;
        int c = (q % CPR) ^ SWZ64(row);
        gA[q0] = A + batch * sA + (long long)(m0 + row) * lda + c * 8;
    }
#pragma unroll
    for (int q0 = 0; q0 < NB; ++q0) {
        int q = tid + 256 * q0;
        int row = q / CPR;
        int c = (q % CPR) ^ SWZ64(row);
        gB[q0] = B + batch * sB + (long long)(n0 + row) * ldb + c * 8;
    }

    floatx4 acc[4][2] = {};
    const int nK = kLen / BKT;

#pragma unroll
    for (int q0 = 0; q0 < NA; ++q0) {
        load_lds16(gA[q0], &As[0][(tid + 256 * q0) * 8]);
        gA[q0] += BKT;
    }
#pragma unroll
    for (int q0 = 0; q0 < NB; ++q0) {
        load_lds16(gB[q0], &Bs[0][(tid + 256 * q0) * 8]);
        gB[q0] += BKT;
    }
    for (int kt = 0; kt < nK; ++kt) {
        const int pb = kt & 1;
        if (kt + 1 < nK) {
#pragma unroll
            for (int q0 = 0; q0 < NA; ++q0) {
                load_lds16(gA[q0], &As[pb ^ 1][(tid + 256 * q0) * 8]);
                gA[q0] += BKT;
            }
#pragma unroll
            for (int q0 = 0; q0 < NB; ++q0) {
                load_lds16(gB[q0], &Bs[pb ^ 1][(tid + 256 * q0) * 8]);
                gB[q0] += BKT;
            }
            WAIT_VM(6);   // current tile landed; 6 next-tile loads in flight
        } else {
            WAIT_VM(0);
        }
        BAR();
        const __hip_bfloat16* Ab = &As[pb][0];
        const __hip_bfloat16* Bb = &Bs[pb][0];
#pragma unroll
        for (int kk = 0; kk < BKT / 32; ++kk) {
            const int cidx = kk * 4 + hi;
            bf16x8 af[4], bfr[2];
#pragma unroll
            for (int i = 0; i < 4; ++i) {
                int row = i * 16 + ln;
                af[i] = *(const bf16x8*)(Ab + row * BKT + ((cidx ^ SWZ64(row)) << 3));
            }
#pragma unroll
            for (int j = 0; j < 2; ++j) {
                int row = w * 32 + j * 16 + ln;
                bfr[j] = *(const bf16x8*)(Bb + row * BKT + ((cidx ^ SWZ64(row)) << 3));
            }
#pragma unroll
            for (int i = 0; i < 4; ++i)
#pragma unroll
                for (int j = 0; j < 2; ++j)
                    acc[i][j] = __builtin_amdgcn_mfma_f32_16x16x32_bf16(af[i], bfr[j], acc[i][j], 0, 0, 0);
        }
        BAR();
    }

    float* Cb = C + batch * sC;
    const float* xb = xres + batch * sX;
#pragma unroll
    for (int i = 0; i < 4; ++i) {
        int mb = m0 + i * 16 + hi * 4;
#pragma unroll
        for (int r = 0; r < 4; ++r) {
            float bb = bias[batch * sBias + mb + r];
#pragma unroll
            for (int j = 0; j < 2; ++j) {
                int nl = n0 + w * 32 + j * 16 + ln;
                if (nl < Nreal) {
                    long long off = (long long)(mb + r) * ldc + nl;
                    Cb[off] = acc[i][j][r] + bb + xb[off];
                }
            }
        }
    }
}

extern "C" void kernel_launch(void* const* d_in, const int* in_sizes, int n_in,
                              void* d_out, int out_size, void* d_ws, size_t ws_size,
                              hipStream_t stream)
{
    const float* x  = (const float*)d_in[0];
    const float* wq = (const float*)d_in[1];
    const float* bq = (const float*)d_in[2];
    const float* wk = (const float*)d_in[3];
    const float* bk = (const float*)d_in[4];
    const float* wv = (const float*)d_in[5];
    const float* bv = (const float*)d_in[6];
    const float* wo = (const float*)d_in[7];
    const float* bo = (const float*)d_in[8];
    float* out = (float*)d_out;

    const int N = 3136;
    const long long xs = 512LL * N;
    const long long xs2 = 512LL * 3200;

    char* ob = (char*)d_out;
    __hip_bfloat16* xnp = (__hip_bfloat16*)ob;                 // 26,214,400 (dead after G)
    __hip_bfloat16* Gp2 = (__hip_bfloat16*)(ob + 26214400);    //  8,388,608
    __hip_bfloat16* Tb  = (__hip_bfloat16*)(ob + 34603008);    //  4,194,304

    char* wsb = (char*)d_ws;
    __hip_bfloat16* xT  = (__hip_bfloat16*)wsb;                // 26,214,400
    __hip_bfloat16* A2b = (__hip_bfloat16*)(wsb + 26214400);   //  4,194,304
    __hip_bfloat16* Pdb = (__hip_bfloat16*)(wsb + 30408704);   //  1,048,576
    __hip_bfloat16* Qtb = (__hip_bfloat16*)(wsb + 31457280);   //    524,288
    float* sv  = (float*)(wsb + 31981568);
    float* u_  = (float*)(wsb + 31997952);
    float* r_  = (float*)(wsb + 32000000);
    float* w_  = (float*)(wsb + 32002048);
    float* kap = (float*)(wsb + 32004096);
    float* ps  = (float*)(wsb + 32004112);
    float* sq  = (float*)(wsb + 32020496);
    float* a2v = (float*)(wsb + 32036880);

    prep_all<<<dim3(8, 8, 3), 256, 0, stream>>>(wo, wv, wq, wk, bq, bk, bv,
                                                Pdb, Qtb, u_, r_, w_, kap, sv);

    transpose_conv<<<dim3(50, 8, 8), 256, 0, stream>>>(x, xT, xnp, sv);

    mfma_g<<<dim3(16, 36), 256, 0, stream>>>(
        xnp, xs2, 3200, Gp2, 524288, 1024, 1600);

    mfma_sm<5><<<dim3(8, 8, 8), 256, 0, stream>>>(
        Pdb, 0, 1024, Gp2, 524288, 1024, Tb, 262144, 512,
        nullptr, nullptr, nullptr, nullptr, 1024);

    vec2_kernel<<<1024, 256, 0, stream>>>(Tb, Pdb, Qtb, sv, u_, w_, kap, bo, ps, sq, a2v);

    mfma_sm<6><<<dim3(8, 8, 8), 256, 0, stream>>>(
        Tb, 262144, 512, Qtb, 0, 512, A2b, 262144, 512,
        u_, r_, ps, sq, 512);

    mfma64<<<dim3(8, 25, 8), 256, 0, stream>>>(
        A2b, 262144, 512, xT, 3200LL * 512, 512,
        out, xs, N, a2v, 512, x, xs, 512, N);
}